// Round 2
// baseline (127.847 us; speedup 1.0000x reference)
//
#include <hip/hip_runtime.h>
#include <math.h>

// Problem constants (reference: N=1024, D=128, tau=1, beta=1)
#define NN 1024
#define DD 128
#define JCH 8        // j-chunks per pair (each chunk = 128 columns)

typedef __bf16 bf16x8 __attribute__((ext_vector_type(8)));
typedef float  floatx4 __attribute__((ext_vector_type(4)));

// ws layout (bytes):
//   0        : bf16 matrices [3][1024][128]  (x, lp, aug)   = 786432
//   786432   : norms  [3][1024] f32                         = 12288  (ends 798720)
//   798720   : denom  [2][1024] f32 (atomic-accumulated)    = 8192   (ends 806912)
//   806912   : pos    [2][1024] f32                         = 8192   (ends 815104)
//   815104   : acc[2] f32 loss partials                     = 8      (ends 815112)
//   815112   : tile counters [128] u32                      = 512    (ends 815624)
//   815624   : global counter [1] u32
#define WS_NORMS  786432
#define WS_DENOM  798720
#define WS_POS    806912
#define WS_ACC    815104
#define WS_TCNT   815112
#define WS_GCNT   815624
#define ZERO_WORDS 4227   // (815628 - 798720) / 4

// ---------------- prep: fp32 -> bf16 + row norms + zero reduction state -----
// grid 768 x 256: one wave per row, 3*1024 rows total.
__global__ __launch_bounds__(256) void align_prep(
    const float* __restrict__ x, const float* __restrict__ lp,
    const float* __restrict__ aug, __bf16* __restrict__ mats,
    float* __restrict__ norms, unsigned* __restrict__ zero_base)
{
    // zero denom/pos/acc/counters: 4227 words, blocks 0..16 cover 17*256=4352
    if (blockIdx.x < 17) {
        const unsigned zi = blockIdx.x * 256 + threadIdx.x;
        if (zi < ZERO_WORDS) zero_base[zi] = 0u;
    }

    const int w    = threadIdx.x >> 6;
    const int lane = threadIdx.x & 63;
    const int gw   = blockIdx.x * 4 + w;          // 0..3071
    const int a    = gw >> 10;                    // array 0..2
    const int r    = gw & 1023;                   // row
    const float* src = (a == 0 ? x : (a == 1 ? lp : aug)) + (size_t)r * DD + lane * 2;
    const float2 v = *(const float2*)src;
    float sq = v.x * v.x + v.y * v.y;
    union { __bf16 b[2]; unsigned u; } t;
    t.b[0] = (__bf16)v.x; t.b[1] = (__bf16)v.y;
    *(unsigned*)(mats + (size_t)a * (NN * DD) + (size_t)r * DD + lane * 2) = t.u;
#pragma unroll
    for (int m = 1; m < 64; m <<= 1) sq += __shfl_xor(sq, m);
    if (lane == 0) norms[a * NN + r] = sq;
}

// ---------------- pair kernel with fused reduction tail ---------------------
// grid (64, 2, JCH), block 256 (4 waves). Wave w covers j = jc*128 + t*64 + w*16,
// t = 0..1. d2_ij = nx_i + ny_j - 2*dot; dot via bf16 MFMA.
// Each block atomicAdds its 16 per-row denominator partials; the 8th finisher
// per (tile,pair) computes pos - log(den); the 128th tile-finisher writes out.
__global__ __launch_bounds__(256) void align_pair_kernel(
    const __bf16* __restrict__ mats, const float* __restrict__ norms,
    float* __restrict__ denom, float* __restrict__ posb,
    float* __restrict__ acc, unsigned* __restrict__ tcnt,
    unsigned* __restrict__ gcnt, float* __restrict__ out)
{
    const float SCALE = 0.08838834764831845f;  // 1/sqrt(128)
    const int bx = blockIdx.x;     // i-tile (16 rows)
    const int p  = blockIdx.y;     // 0: x vs lp, 1: x vs aug
    const int jc = blockIdx.z;     // j-chunk (128 cols)
    const __bf16* __restrict__ A = mats;                              // x
    const __bf16* __restrict__ B = mats + (size_t)(p ? 2 : 1) * (NN * DD);
    const float*  __restrict__ nx = norms;
    const float*  __restrict__ ny = norms + (p ? 2 : 1) * NN;

    const int i0   = bx * 16;
    const int tid  = threadIdx.x;
    const int w    = tid >> 6;
    const int lane = tid & 63;
    const int col  = lane & 15;
    const int quad = lane >> 4;

    // A fragments: row i0+col, k = c*32 + quad*8 + [0..7]
    const __bf16* arow = A + (size_t)(i0 + col) * DD + quad * 8;
    bf16x8 afrag[4];
#pragma unroll
    for (int c = 0; c < 4; ++c) afrag[c] = *(const bf16x8*)(arow + c * 32);
    // norms for this lane's 4 C-rows (row = quad*4 + r)
    const float4 nxr = *(const float4*)(nx + i0 + quad * 4);

    float den4[4] = {0.f, 0.f, 0.f, 0.f};
    float pos4[4] = {0.f, 0.f, 0.f, 0.f};

#pragma unroll
    for (int t = 0; t < 2; ++t) {
        const int j0 = jc * 128 + t * 64 + w * 16;
        const __bf16* brow = B + (size_t)(j0 + col) * DD + quad * 8;
        bf16x8 bfrag[4];
#pragma unroll
        for (int c = 0; c < 4; ++c) bfrag[c] = *(const bf16x8*)(brow + c * 32);
        const float nyv = ny[j0 + col];   // norm of column j0+col

        floatx4 acc4 = {0.f, 0.f, 0.f, 0.f};
#pragma unroll
        for (int c = 0; c < 4; ++c)
            acc4 = __builtin_amdgcn_mfma_f32_16x16x32_bf16(afrag[c], bfrag[c], acc4, 0, 0, 0);

#pragma unroll
        for (int r = 0; r < 4; ++r) {
            const int row = quad * 4 + r;          // C: col=lane&15, row=quad*4+r
            float d2 = fmaf(-2.f, acc4[r], nxr[r] + nyv);
            d2 = fmaxf(d2, 0.f);
            const float dm = SCALE * sqrtf(d2);
            den4[r] += __expf(dm);
            if (j0 + col == i0 + row) pos4[r] = dm;
        }
    }

    // reduce across the 16 cols of each quad group
#pragma unroll
    for (int r = 0; r < 4; ++r) {
#pragma unroll
        for (int m = 1; m < 16; m <<= 1) {
            den4[r] += __shfl_xor(den4[r], m);
            pos4[r] += __shfl_xor(pos4[r], m);
        }
    }

    __shared__ float ld_den[4][16];
    __shared__ float ld_pos[4][16];
    if (col == 0) {
#pragma unroll
        for (int r = 0; r < 4; ++r) {
            ld_den[w][quad * 4 + r] = den4[r];
            ld_pos[w][quad * 4 + r] = pos4[r];
        }
    }
    __syncthreads();

    const bool hasdiag = (jc == (bx >> 3));  // chunk containing the diagonal
    if (tid < 16) {
        const float den = ld_den[0][tid] + ld_den[1][tid] + ld_den[2][tid] + ld_den[3][tid];
        atomicAdd(&denom[p * NN + i0 + tid], den);
        if (hasdiag) {
            const float po = ld_pos[0][tid] + ld_pos[1][tid] + ld_pos[2][tid] + ld_pos[3][tid];
            atomicAdd(&posb[p * NN + i0 + tid], po);
        }
    }
    __threadfence();
    __syncthreads();

    __shared__ unsigned fin;
    if (tid == 0) fin = (atomicAdd(&tcnt[p * 64 + bx], 1u) == JCH - 1) ? 1u : 0u;
    __syncthreads();
    if (!fin) return;

    // 8th finisher for this (tile, pair): complete rows i0..i0+15
    float contrib = 0.f;
    if (tid < 16) {
        const float dsum = atomicAdd(&denom[p * NN + i0 + tid], 0.0f);  // coherent read
        const float psum = atomicAdd(&posb[p * NN + i0 + tid], 0.0f);
        contrib = psum - __logf(dsum);
    }
    if (w == 0) {
#pragma unroll
        for (int m = 1; m < 16; m <<= 1) contrib += __shfl_xor(contrib, m);
    }
    if (tid == 0) {
        atomicAdd(&acc[p], contrib);
        __threadfence();
        if (atomicAdd(gcnt, 1u) == 127u) {   // last of 128 tile-finishers
            const float a  = atomicAdd(&acc[0], 0.0f);
            const float b  = atomicAdd(&acc[1], 0.0f);
            const float inv = 1.0f / (float)NN;
            const float c  = a * inv;   // center alignment loss
            const float ia = b * inv;   // instance alignment loss
            out[0] = c + ia;
            out[1] = c;
            out[2] = ia;
        }
    }
}

extern "C" void kernel_launch(void* const* d_in, const int* in_sizes, int n_in,
                              void* d_out, int out_size, void* d_ws, size_t ws_size,
                              hipStream_t stream) {
    const float* x   = (const float*)d_in[0];
    const float* aug = (const float*)d_in[1];
    const float* lp  = (const float*)d_in[2];
    float* out       = (float*)d_out;

    char* ws = (char*)d_ws;
    __bf16*   mats  = (__bf16*)ws;
    float*    norms = (float*)(ws + WS_NORMS);
    float*    denom = (float*)(ws + WS_DENOM);
    float*    posb  = (float*)(ws + WS_POS);
    float*    acc   = (float*)(ws + WS_ACC);
    unsigned* tcnt  = (unsigned*)(ws + WS_TCNT);
    unsigned* gcnt  = (unsigned*)(ws + WS_GCNT);

    align_prep<<<768, 256, 0, stream>>>(x, lp, aug, mats, norms, (unsigned*)(ws + WS_DENOM));
    align_pair_kernel<<<dim3(64, 2, JCH), 256, 0, stream>>>(
        mats, norms, denom, posb, acc, tcnt, gcnt, out);
}

// Round 3
// 70.711 us; speedup vs baseline: 1.8080x; 1.8080x over previous
//
#include <hip/hip_runtime.h>
#include <math.h>

// Problem constants (reference: N=1024, D=128, tau=1, beta=1)
#define NN 1024
#define DD 128
#define JCH 8        // j-chunks per pair (each chunk = 128 columns)

typedef __bf16 bf16x8 __attribute__((ext_vector_type(8)));
typedef float  floatx4 __attribute__((ext_vector_type(4)));

// ws layout (bytes):
//   0      : denom partials [2][JCH][1024] f32 = 65536
//   65536  : pos [2][1024] f32                 = 8192
#define WS_POS 65536

// ---------------- fused prep+pair: per (i-tile, pair, j-chunk) ---------------
// grid (64, 2, JCH), block 256 (4 waves). Wave w covers j = jc*128 + t*64 + w*16,
// t = 0..1. Loads raw f32, converts to bf16 fragments in-register; row norms
// accumulate during conversion (lane's 4 k-slices tile the full 128-wide row,
// quads complete it -> shfl_xor(16/32) gives ||row||^2). No prep kernel, no
// norms array, no atomics, no fences.
__global__ __launch_bounds__(256) void align_pair_kernel(
    const float* __restrict__ x, const float* __restrict__ lp,
    const float* __restrict__ aug,
    float* __restrict__ denom_part, float* __restrict__ posbuf)
{
    const float SCALE = 0.08838834764831845f;  // 1/sqrt(128)
    const int bx = blockIdx.x;     // i-tile (16 rows)
    const int p  = blockIdx.y;     // 0: x vs lp, 1: x vs aug
    const int jc = blockIdx.z;     // j-chunk (128 cols)
    const float* __restrict__ A = x;
    const float* __restrict__ B = p ? aug : lp;

    const int i0   = bx * 16;
    const int tid  = threadIdx.x;
    const int w    = tid >> 6;
    const int lane = tid & 63;
    const int col  = lane & 15;
    const int quad = lane >> 4;

    // A fragments: row i0+col, k = c*32 + quad*8 + [0..7]; squares for norm.
    const float* arow = A + (size_t)(i0 + col) * DD + quad * 8;
    bf16x8 afrag[4];
    float  asq = 0.f;
#pragma unroll
    for (int c = 0; c < 4; ++c) {
        const float4 a0 = *(const float4*)(arow + c * 32);
        const float4 a1 = *(const float4*)(arow + c * 32 + 4);
        bf16x8 f;
        f[0] = (__bf16)a0.x; f[1] = (__bf16)a0.y; f[2] = (__bf16)a0.z; f[3] = (__bf16)a0.w;
        f[4] = (__bf16)a1.x; f[5] = (__bf16)a1.y; f[6] = (__bf16)a1.z; f[7] = (__bf16)a1.w;
        afrag[c] = f;
        asq = fmaf(a0.x, a0.x, asq); asq = fmaf(a0.y, a0.y, asq);
        asq = fmaf(a0.z, a0.z, asq); asq = fmaf(a0.w, a0.w, asq);
        asq = fmaf(a1.x, a1.x, asq); asq = fmaf(a1.y, a1.y, asq);
        asq = fmaf(a1.z, a1.z, asq); asq = fmaf(a1.w, a1.w, asq);
    }
    // complete ||row i0+col||^2 across the 4 quads
    asq += __shfl_xor(asq, 16);
    asq += __shfl_xor(asq, 32);
    __shared__ float nA[16];
    if (tid < 16) nA[tid] = asq;          // wave 0, quad 0: col == tid
    __syncthreads();
    // norms for this lane's 4 C-rows (row = quad*4 + r)
    const float4 nxr = *(const float4*)(&nA[quad * 4]);

    float den4[4] = {0.f, 0.f, 0.f, 0.f};
    float pos4[4] = {0.f, 0.f, 0.f, 0.f};

#pragma unroll
    for (int t = 0; t < 2; ++t) {
        const int j0 = jc * 128 + t * 64 + w * 16;
        const float* brow = B + (size_t)(j0 + col) * DD + quad * 8;
        bf16x8 bfrag[4];
        float  bsq = 0.f;
#pragma unroll
        for (int c = 0; c < 4; ++c) {
            const float4 b0 = *(const float4*)(brow + c * 32);
            const float4 b1 = *(const float4*)(brow + c * 32 + 4);
            bf16x8 f;
            f[0] = (__bf16)b0.x; f[1] = (__bf16)b0.y; f[2] = (__bf16)b0.z; f[3] = (__bf16)b0.w;
            f[4] = (__bf16)b1.x; f[5] = (__bf16)b1.y; f[6] = (__bf16)b1.z; f[7] = (__bf16)b1.w;
            bfrag[c] = f;
            bsq = fmaf(b0.x, b0.x, bsq); bsq = fmaf(b0.y, b0.y, bsq);
            bsq = fmaf(b0.z, b0.z, bsq); bsq = fmaf(b0.w, b0.w, bsq);
            bsq = fmaf(b1.x, b1.x, bsq); bsq = fmaf(b1.y, b1.y, bsq);
            bsq = fmaf(b1.z, b1.z, bsq); bsq = fmaf(b1.w, b1.w, bsq);
        }
        // complete ||row j0+col||^2 across quads: lane-local ny
        bsq += __shfl_xor(bsq, 16);
        bsq += __shfl_xor(bsq, 32);
        const float nyv = bsq;

        floatx4 acc4 = {0.f, 0.f, 0.f, 0.f};
#pragma unroll
        for (int c = 0; c < 4; ++c)
            acc4 = __builtin_amdgcn_mfma_f32_16x16x32_bf16(afrag[c], bfrag[c], acc4, 0, 0, 0);

#pragma unroll
        for (int r = 0; r < 4; ++r) {
            const int row = quad * 4 + r;          // C: col=lane&15, row=quad*4+r
            float d2 = fmaf(-2.f, acc4[r], nxr[r] + nyv);
            d2 = fmaxf(d2, 0.f);
            const float dm = SCALE * sqrtf(d2);
            den4[r] += __expf(dm);
            if (j0 + col == i0 + row) pos4[r] = dm;
        }
    }

    // reduce across the 16 cols of each quad group
#pragma unroll
    for (int r = 0; r < 4; ++r) {
#pragma unroll
        for (int m = 1; m < 16; m <<= 1) {
            den4[r] += __shfl_xor(den4[r], m);
            pos4[r] += __shfl_xor(pos4[r], m);
        }
    }

    __shared__ float ld_den[4][16];
    __shared__ float ld_pos[4][16];
    if (col == 0) {
#pragma unroll
        for (int r = 0; r < 4; ++r) {
            ld_den[w][quad * 4 + r] = den4[r];
            ld_pos[w][quad * 4 + r] = pos4[r];
        }
    }
    __syncthreads();
    if (tid < 16) {
        const float den = ld_den[0][tid] + ld_den[1][tid] + ld_den[2][tid] + ld_den[3][tid];
        denom_part[(size_t)(p * JCH + jc) * NN + i0 + tid] = den;
        if (jc == (bx >> 3)) {   // this chunk contains the diagonal for rows i0..i0+15
            const float po = ld_pos[0][tid] + ld_pos[1][tid] + ld_pos[2][tid] + ld_pos[3][tid];
            posbuf[p * NN + i0 + tid] = po;
        }
    }
}

// ---------------- finalize: 1 block, 1024 threads (thread = row) -------------
__global__ __launch_bounds__(1024) void align_finalize(
    const float* __restrict__ denom_part, const float* __restrict__ posbuf,
    float* __restrict__ out)
{
    const int tid  = threadIdx.x;   // row 0..1023
    const int w    = tid >> 6;
    const int lane = tid & 63;
    float contrib[2];
#pragma unroll
    for (int p = 0; p < 2; ++p) {
        float den = 0.f;
#pragma unroll
        for (int jc = 0; jc < JCH; ++jc)
            den += denom_part[(size_t)(p * JCH + jc) * NN + tid];
        contrib[p] = posbuf[p * NN + tid] - __logf(den);
    }
    float c0 = contrib[0], c1 = contrib[1];
#pragma unroll
    for (int m = 1; m < 64; m <<= 1) {
        c0 += __shfl_xor(c0, m);
        c1 += __shfl_xor(c1, m);
    }
    __shared__ float s0[16], s1[16];
    if (lane == 0) { s0[w] = c0; s1[w] = c1; }
    __syncthreads();
    if (tid == 0) {
        float a = 0.f, b = 0.f;
#pragma unroll
        for (int k = 0; k < 16; ++k) { a += s0[k]; b += s1[k]; }
        const float inv = 1.0f / (float)NN;
        const float c  = a * inv;   // center alignment loss
        const float ia = b * inv;   // instance alignment loss
        out[0] = c + ia;
        out[1] = c;
        out[2] = ia;
    }
}

extern "C" void kernel_launch(void* const* d_in, const int* in_sizes, int n_in,
                              void* d_out, int out_size, void* d_ws, size_t ws_size,
                              hipStream_t stream) {
    const float* x   = (const float*)d_in[0];
    const float* aug = (const float*)d_in[1];
    const float* lp  = (const float*)d_in[2];
    float* out       = (float*)d_out;

    char* ws = (char*)d_ws;
    float* denom_par = (float*)ws;
    float* posbuf    = (float*)(ws + WS_POS);

    align_pair_kernel<<<dim3(64, 2, JCH), 256, 0, stream>>>(
        x, lp, aug, denom_par, posbuf);
    align_finalize<<<1, 1024, 0, stream>>>(denom_par, posbuf, out);
}

// Round 4
// 69.723 us; speedup vs baseline: 1.8336x; 1.0142x over previous
//
#include <hip/hip_runtime.h>
#include <math.h>

// Problem constants (reference: N=1024, D=128, tau=1, beta=1)
#define NN 1024
#define DD 128
#define JCH 8        // j-chunks per pair (each chunk = 128 columns)

typedef __bf16 bf16x8 __attribute__((ext_vector_type(8)));
typedef float  floatx4 __attribute__((ext_vector_type(4)));

// ws layout (bytes):
//   0      : bf16 matrices [3][1024][128]  (x, lp, aug)     = 786432
//   786432 : norms [3][1024] f32                            = 12288  (ends 798720)
//   798720 : denA [2*64][8][16] f32 slot-exchanged partials = 65536  (ends 864256)
//   864256 : posA [2*64][16] f32 slot-exchanged diag terms  = 8192   (ends 872448)
//   872448 : acc[2] f32 loss partials (zeroed by prep)      = 8
//   872456 : tcnt [2*64] u32 tile counters (zeroed by prep) = 512
//   872968 : gcnt u32 (zeroed by prep)
#define WS_NORMS 786432
#define WS_DEN   798720
#define WS_POSA  864256
#define WS_ACC   872448
#define ZERO_WORDS 131   // acc(2) + tcnt(128) + gcnt(1)

// ---------------- prep: fp32 -> bf16 + row norms + zero counters ------------
// grid 768 x 256: one wave per row, 3*1024 rows total.
__global__ __launch_bounds__(256) void align_prep(
    const float* __restrict__ x, const float* __restrict__ lp,
    const float* __restrict__ aug, __bf16* __restrict__ mats,
    float* __restrict__ norms, unsigned* __restrict__ zero_base)
{
    if (blockIdx.x == 0 && threadIdx.x < ZERO_WORDS) zero_base[threadIdx.x] = 0u;

    const int w    = threadIdx.x >> 6;
    const int lane = threadIdx.x & 63;
    const int gw   = blockIdx.x * 4 + w;          // 0..3071
    const int a    = gw >> 10;                    // array 0..2
    const int r    = gw & 1023;                   // row
    const float* src = (a == 0 ? x : (a == 1 ? lp : aug)) + (size_t)r * DD + lane * 2;
    const float2 v = *(const float2*)src;
    float sq = v.x * v.x + v.y * v.y;
    union { __bf16 b[2]; unsigned u; } t;
    t.b[0] = (__bf16)v.x; t.b[1] = (__bf16)v.y;
    *(unsigned*)(mats + (size_t)a * (NN * DD) + (size_t)r * DD + lane * 2) = t.u;
#pragma unroll
    for (int m = 1; m < 64; m <<= 1) sq += __shfl_xor(sq, m);
    if (lane == 0) norms[a * NN + r] = sq;
}

// ---------------- pair kernel with fence-free fused finalize -----------------
// grid (64, 2, JCH), block 256 (4 waves). Wave w covers j = jc*128 + t*64 + w*16,
// t = 0..1. d2_ij = nx_i + ny_j - 2*dot; dot via bf16 MFMA.
// Tail: slot atomicExch -> syncthreads (drains vmcnt) -> tile counter; 8th
// finisher per (tile,pair) combines chunks; 128th finisher writes outputs.
// NO __threadfence (R2 showed per-block L2 writeback costs ~65 us).
__global__ __launch_bounds__(256) void align_pair_kernel(
    const __bf16* __restrict__ mats, const float* __restrict__ norms,
    float* __restrict__ denA, float* __restrict__ posA,
    float* __restrict__ acc, unsigned* __restrict__ tcnt,
    unsigned* __restrict__ gcnt, float* __restrict__ out)
{
    const float SCALE = 0.08838834764831845f;  // 1/sqrt(128)
    const int bx = blockIdx.x;     // i-tile (16 rows)
    const int p  = blockIdx.y;     // 0: x vs lp, 1: x vs aug
    const int jc = blockIdx.z;     // j-chunk (128 cols)
    const __bf16* __restrict__ A = mats;                              // x
    const __bf16* __restrict__ B = mats + (size_t)(p ? 2 : 1) * (NN * DD);
    const float*  __restrict__ nx = norms;
    const float*  __restrict__ ny = norms + (p ? 2 : 1) * NN;

    const int i0   = bx * 16;
    const int tid  = threadIdx.x;
    const int w    = tid >> 6;
    const int lane = tid & 63;
    const int col  = lane & 15;
    const int quad = lane >> 4;

    // A fragments: row i0+col, k = c*32 + quad*8 + [0..7]
    const __bf16* arow = A + (size_t)(i0 + col) * DD + quad * 8;
    bf16x8 afrag[4];
#pragma unroll
    for (int c = 0; c < 4; ++c) afrag[c] = *(const bf16x8*)(arow + c * 32);
    // norms for this lane's 4 C-rows (row = quad*4 + r)
    const float4 nxr = *(const float4*)(nx + i0 + quad * 4);

    float den4[4] = {0.f, 0.f, 0.f, 0.f};
    float pos4[4] = {0.f, 0.f, 0.f, 0.f};

#pragma unroll
    for (int t = 0; t < 2; ++t) {
        const int j0 = jc * 128 + t * 64 + w * 16;
        const __bf16* brow = B + (size_t)(j0 + col) * DD + quad * 8;
        bf16x8 bfrag[4];
#pragma unroll
        for (int c = 0; c < 4; ++c) bfrag[c] = *(const bf16x8*)(brow + c * 32);
        const float nyv = ny[j0 + col];   // norm of column j0+col

        floatx4 acc4 = {0.f, 0.f, 0.f, 0.f};
#pragma unroll
        for (int c = 0; c < 4; ++c)
            acc4 = __builtin_amdgcn_mfma_f32_16x16x32_bf16(afrag[c], bfrag[c], acc4, 0, 0, 0);

#pragma unroll
        for (int r = 0; r < 4; ++r) {
            const int row = quad * 4 + r;          // C: col=lane&15, row=quad*4+r
            float d2 = fmaf(-2.f, acc4[r], nxr[r] + nyv);
            d2 = fmaxf(d2, 0.f);
            const float dm = SCALE * sqrtf(d2);
            den4[r] += __expf(dm);
            if (j0 + col == i0 + row) pos4[r] = dm;
        }
    }

    // reduce across the 16 cols of each quad group
#pragma unroll
    for (int r = 0; r < 4; ++r) {
#pragma unroll
        for (int m = 1; m < 16; m <<= 1) {
            den4[r] += __shfl_xor(den4[r], m);
            pos4[r] += __shfl_xor(pos4[r], m);
        }
    }

    __shared__ float ld_den[4][16];
    __shared__ float ld_pos[4][16];
    if (col == 0) {
#pragma unroll
        for (int r = 0; r < 4; ++r) {
            ld_den[w][quad * 4 + r] = den4[r];
            ld_pos[w][quad * 4 + r] = pos4[r];
        }
    }
    __syncthreads();

    const int  grp     = p * 64 + bx;          // 0..127
    const bool hasdiag = (jc == (bx >> 3));    // chunk containing the diagonal
    if (tid < 16) {
        const float den = ld_den[0][tid] + ld_den[1][tid] + ld_den[2][tid] + ld_den[3][tid];
        atomicExch(&denA[(grp * JCH + jc) * 16 + tid], den);  // coherent slot write
        if (hasdiag) {
            const float po = ld_pos[0][tid] + ld_pos[1][tid] + ld_pos[2][tid] + ld_pos[3][tid];
            atomicExch(&posA[grp * 16 + tid], po);
        }
    }
    __syncthreads();   // compiler drains vmcnt before s_barrier -> exchs complete

    __shared__ unsigned finsh;
    if (tid == 0) finsh = (atomicAdd(&tcnt[grp], 1u) == JCH - 1) ? 1u : 0u;
    __syncthreads();
    if (!finsh) return;

    // 8th finisher for this (tile, pair): combine the 8 chunk partials
    __shared__ float sden[JCH][16];
    if (tid < 128) {
        const int jr = tid >> 4, row = tid & 15;
        sden[jr][row] = atomicAdd(&denA[(grp * JCH + jr) * 16 + row], 0.0f);  // coherent read
    }
    float psum = 0.f;
    if (tid < 16) psum = atomicAdd(&posA[grp * 16 + tid], 0.0f);
    __syncthreads();

    float contrib = 0.f;
    if (tid < 16) {
        float dsum = 0.f;
#pragma unroll
        for (int k = 0; k < JCH; ++k) dsum += sden[k][tid];
        contrib = psum - __logf(dsum);
    }
    if (w == 0) {
#pragma unroll
        for (int m = 1; m < 16; m <<= 1) contrib += __shfl_xor(contrib, m);
    }
    if (tid == 0) {
        const float oldacc = atomicAdd(&acc[p], contrib);
        unsigned bump = 1u;
        asm volatile("" : "+v"(bump) : "v"(oldacc));  // order: gcnt after acc-add completes
        if (atomicAdd(gcnt, bump) == 127u) {          // last of 128 tile-finishers
            const float a  = atomicAdd(&acc[0], 0.0f);
            const float b  = atomicAdd(&acc[1], 0.0f);
            const float inv = 1.0f / (float)NN;
            const float c  = a * inv;   // center alignment loss
            const float ia = b * inv;   // instance alignment loss
            out[0] = c + ia;
            out[1] = c;
            out[2] = ia;
        }
    }
}

extern "C" void kernel_launch(void* const* d_in, const int* in_sizes, int n_in,
                              void* d_out, int out_size, void* d_ws, size_t ws_size,
                              hipStream_t stream) {
    const float* x   = (const float*)d_in[0];
    const float* aug = (const float*)d_in[1];
    const float* lp  = (const float*)d_in[2];
    float* out       = (float*)d_out;

    char* ws = (char*)d_ws;
    __bf16*   mats  = (__bf16*)ws;
    float*    norms = (float*)(ws + WS_NORMS);
    float*    denA  = (float*)(ws + WS_DEN);
    float*    posA  = (float*)(ws + WS_POSA);
    float*    acc   = (float*)(ws + WS_ACC);
    unsigned* tcnt  = (unsigned*)(ws + WS_ACC + 8);
    unsigned* gcnt  = (unsigned*)(ws + WS_ACC + 8 + 512);

    align_prep<<<768, 256, 0, stream>>>(x, lp, aug, mats, norms, (unsigned*)(ws + WS_ACC));
    align_pair_kernel<<<dim3(64, 2, JCH), 256, 0, stream>>>(
        mats, norms, denA, posA, acc, tcnt, gcnt, out);
}